// Round 1
// baseline (349.110 us; speedup 1.0000x reference)
//
#include <hip/hip_runtime.h>

#define F_ 256
#define S_ 512
#define NH_ 16
#define DQ_ 64
#define CH_ 32

__device__ __forceinline__ float sigmoid_f(float x) { return 1.0f / (1.0f + __expf(-x)); }

template<int CTRL>
__device__ __forceinline__ float dpp_add(float x) {
  int y = __builtin_amdgcn_update_dpp(0, __float_as_int(x), CTRL, 0xf, 0xf, true);
  return x + __int_as_float(y);
}

// butterfly sum over each aligned 16-lane group; result broadcast to all 16 lanes
__device__ __forceinline__ float red16(float x) {
  x = dpp_add<0xB1>(x);   // quad_perm [1,0,3,2]  (xor 1)
  x = dpp_add<0x4E>(x);   // quad_perm [2,3,0,1]  (xor 2)
  x = dpp_add<0x141>(x);  // row_half_mirror      (pairs l <-> l^7 in 8)
  x = dpp_add<0x140>(x);  // row_mirror           (pairs l <-> l^15 in 16)
  return x;
}

// C = act(A @ W + bias); A: MxK row-major, W: KxN row-major. BM=BN=64, BK=32.
__global__ __launch_bounds__(256) void gemm_f32_k(
    const float* __restrict__ A, const float* __restrict__ W,
    const float* __restrict__ bias, float* __restrict__ C,
    int M, int N, int K, int act)
{
  __shared__ float As[32][64];   // transposed A tile: As[k][m]
  __shared__ float Bs[32][64];   // Bs[k][n]
  const int tid = threadIdx.x;
  const int tx = tid & 15;
  const int ty = tid >> 4;
  const int row0 = blockIdx.y * 64;
  const int col0 = blockIdx.x * 64;
  float acc[4][4];
  #pragma unroll
  for (int i = 0; i < 4; ++i)
    #pragma unroll
    for (int j = 0; j < 4; ++j) acc[i][j] = 0.0f;

  for (int k0 = 0; k0 < K; k0 += 32) {
    #pragma unroll
    for (int p = 0; p < 2; ++p) {
      {
        const int r  = p * 32 + (tid >> 3);
        const int kk = (tid & 7) << 2;
        const float4 av = *(const float4*)&A[(size_t)(row0 + r) * K + k0 + kk];
        As[kk + 0][r] = av.x;
        As[kk + 1][r] = av.y;
        As[kk + 2][r] = av.z;
        As[kk + 3][r] = av.w;
      }
      {
        const int rb = p * 16 + ty;
        const int cc = tx << 2;
        *(float4*)&Bs[rb][cc] = *(const float4*)&W[(size_t)(k0 + rb) * N + col0 + cc];
      }
    }
    __syncthreads();
    #pragma unroll
    for (int kk = 0; kk < 32; ++kk) {
      const float4 a4 = *(const float4*)&As[kk][ty << 2];
      const float4 b4 = *(const float4*)&Bs[kk][tx << 2];
      const float av[4] = {a4.x, a4.y, a4.z, a4.w};
      const float bv[4] = {b4.x, b4.y, b4.z, b4.w};
      #pragma unroll
      for (int i = 0; i < 4; ++i)
        #pragma unroll
        for (int j = 0; j < 4; ++j)
          acc[i][j] += av[i] * bv[j];
    }
    __syncthreads();
  }

  #pragma unroll
  for (int i = 0; i < 4; ++i) {
    const int row = row0 + (ty << 2) + i;
    const int col = col0 + (tx << 2);
    float4 r = make_float4(acc[i][0], acc[i][1], acc[i][2], acc[i][3]);
    if (bias) {
      const float4 b = *(const float4*)&bias[col];
      r.x += b.x; r.y += b.y; r.z += b.z; r.w += b.w;
    }
    if (act == 1) {
      r.x *= sigmoid_f(r.x); r.y *= sigmoid_f(r.y);
      r.z *= sigmoid_f(r.z); r.w *= sigmoid_f(r.w);
    }
    *(float4*)&C[(size_t)row * N + col] = r;
  }
}

// in-place row L2-normalize (k / max(||k||, 1e-12)), one wave per 256-float row
__global__ __launch_bounds__(256) void knorm_k(float* __restrict__ k)
{
  const int lane = threadIdx.x & 63;
  const size_t row = ((size_t)blockIdx.x << 2) + (threadIdx.x >> 6);
  const size_t off = row * F_ + ((size_t)lane << 2);
  float4 v = *(float4*)&k[off];
  float ss = v.x * v.x + v.y * v.y + v.z * v.z + v.w * v.w;
  #pragma unroll
  for (int m = 1; m < 64; m <<= 1) ss += __shfl_xor(ss, m, 64);
  const float nrm = sqrtf(ss);
  const float sc = 1.0f / fmaxf(nrm, 1e-12f);
  v.x *= sc; v.y *= sc; v.z *= sc; v.w *= sc;
  *(float4*)&k[off] = v;
}

// eta = sigmoid(se @ We2 + be2)*0.1 + 0.01 ; alpha = sigmoid(sa @ Wa2 + ba2)*0.5 + 0.5
__global__ __launch_bounds__(256) void etaalpha_k(
    const float* __restrict__ se, const float* __restrict__ sa,
    const float* __restrict__ We2, const float* __restrict__ be2,
    const float* __restrict__ Wa2, const float* __restrict__ ba2,
    float* __restrict__ eta, float* __restrict__ alpha)
{
  const int lane = threadIdx.x & 63;
  const size_t row = ((size_t)blockIdx.x << 2) + (threadIdx.x >> 6);
  float pe = se[row * DQ_ + lane] * We2[lane];
  float pa = sa[row * DQ_ + lane] * Wa2[lane];
  #pragma unroll
  for (int m = 1; m < 64; m <<= 1) {
    pe += __shfl_xor(pe, m, 64);
    pa += __shfl_xor(pa, m, 64);
  }
  if (lane == 0) {
    eta[row]   = sigmoid_f(pe + be2[0]) * 0.1f + 0.01f;
    alpha[row] = sigmoid_f(pa + ba2[0]) * 0.5f + 0.5f;
  }
}

// y = LN(t + x) * gamma + beta ; one wave per 256-float row (t already includes bo)
__global__ __launch_bounds__(256) void ln_k(
    const float* __restrict__ t, const float* __restrict__ x,
    const float* __restrict__ gamma, const float* __restrict__ beta,
    float* __restrict__ y)
{
  const int lane = threadIdx.x & 63;
  const size_t row = ((size_t)blockIdx.x << 2) + (threadIdx.x >> 6);
  const size_t off = row * F_ + ((size_t)lane << 2);
  const float4 tv = *(const float4*)&t[off];
  const float4 xv = *(const float4*)&x[off];
  float4 v = make_float4(tv.x + xv.x, tv.y + xv.y, tv.z + xv.z, tv.w + xv.w);
  float sm = v.x + v.y + v.z + v.w;
  float sq = v.x * v.x + v.y * v.y + v.z * v.z + v.w * v.w;
  #pragma unroll
  for (int m = 1; m < 64; m <<= 1) {
    sm += __shfl_xor(sm, m, 64);
    sq += __shfl_xor(sq, m, 64);
  }
  const float mu  = sm * (1.0f / 256.0f);
  const float var = sq * (1.0f / 256.0f) - mu * mu;
  const float rstd = rsqrtf(var + 1e-5f);
  const float4 g = *(const float4*)&gamma[(size_t)lane << 2];
  const float4 b = *(const float4*)&beta[(size_t)lane << 2];
  float4 o;
  o.x = (v.x - mu) * rstd * g.x + b.x;
  o.y = (v.y - mu) * rstd * g.y + b.y;
  o.z = (v.z - mu) * rstd * g.z + b.z;
  o.w = (v.w - mu) * rstd * g.w + b.w;
  *(float4*)&y[off] = o;
}

// Gated delta-rule scan. Grid (16 row-blocks, 16 heads), block 256.
// Thread (row=tid>>4, sub=tid&15) owns M[rb*16+row][sub*16 .. sub*16+16) in regs.
__global__ __launch_bounds__(256) void scan_k(
    const float* __restrict__ q, const float* __restrict__ kn,
    const float* __restrict__ vh, const float* __restrict__ eta,
    const float* __restrict__ alpha, float* __restrict__ out,
    float* __restrict__ Mout)
{
  __shared__ float qs[CH_ * F_];
  __shared__ float ks[CH_ * F_];
  __shared__ float vs[CH_ * 16];
  __shared__ float es[CH_];
  __shared__ float as_[CH_];
  __shared__ float os[CH_ * 16];

  const int tid = threadIdx.x;
  const int row = tid >> 4;      // 0..15 local row
  const int sub = tid & 15;      // 0..15 column chunk
  const int rb = blockIdx.x;     // row-block within head
  const int h  = blockIdx.y;     // head
  const int ig = rb * 16 + row;  // global row in head

  const float* qh  = q   + (size_t)h * S_ * F_;
  const float* kh  = kn  + (size_t)h * S_ * F_;
  const float* vhh = vh  + (size_t)h * S_ * F_ + rb * 16;
  const float* eh  = eta   + (size_t)h * S_;
  const float* ah  = alpha + (size_t)h * S_;

  float M[16];
  #pragma unroll
  for (int j = 0; j < 16; ++j) M[j] = 0.0f;

  const int swz = ((sub >> 1) & 3) << 2;   // XOR swizzle: kills 8-way bank conflicts

  for (int t0 = 0; t0 < S_; t0 += CH_) {
    // stage q,k chunk (swizzled), coalesced float4 global loads
    #pragma unroll
    for (int u = 0; u < CH_ * F_ / 4; u += 256) {
      const int i4 = u + tid;
      const int t  = i4 >> 6;
      const int c  = (i4 & 63) << 2;
      const int cp = c ^ ((((c >> 5) & 3)) << 2);
      const float4 qv = *(const float4*)&qh[(size_t)(t0 + t) * F_ + c];
      const float4 kv = *(const float4*)&kh[(size_t)(t0 + t) * F_ + c];
      *(float4*)&qs[t * F_ + cp] = qv;
      *(float4*)&ks[t * F_ + cp] = kv;
    }
    // stage v-slice (this block's 16 rows), eta, alpha
    #pragma unroll
    for (int u = tid; u < CH_ * 16; u += 256) {
      const int t = u >> 4, r = u & 15;
      vs[u] = vhh[(size_t)(t0 + t) * F_ + r];
    }
    if (tid < CH_)            es[tid]        = eh[t0 + tid];
    else if (tid < 2 * CH_)   as_[tid - CH_] = ah[t0 + tid - CH_];
    __syncthreads();

    for (int t = 0; t < CH_; ++t) {
      float kreg[16];
      float dqa[4], dka[4];
      #pragma unroll
      for (int u = 0; u < 4; ++u) {
        const int c = ((sub << 4) + (u << 2)) ^ swz;
        const float4 q4 = *(const float4*)&qs[t * F_ + c];
        const float4 k4 = *(const float4*)&ks[t * F_ + c];
        kreg[(u << 2) + 0] = k4.x;
        kreg[(u << 2) + 1] = k4.y;
        kreg[(u << 2) + 2] = k4.z;
        kreg[(u << 2) + 3] = k4.w;
        const float* mp = &M[u << 2];
        dqa[u] = mp[0] * q4.x + mp[1] * q4.y + mp[2] * q4.z + mp[3] * q4.w;
        dka[u] = mp[0] * k4.x + mp[1] * k4.y + mp[2] * k4.z + mp[3] * k4.w;
      }
      float dq = (dqa[0] + dqa[1]) + (dqa[2] + dqa[3]);
      float dk = (dka[0] + dka[1]) + (dka[2] + dka[3]);
      dq = red16(dq);
      dk = red16(dk);
      if (sub == 0) os[(t << 4) + row] = dq;   // out_t uses PRE-update M
      const float c_ = es[t] * (vs[(t << 4) + row] - dk);
      const float a_ = as_[t];
      #pragma unroll
      for (int j = 0; j < 16; ++j) M[j] = a_ * M[j] + c_ * kreg[j];
    }
    __syncthreads();

    // write out chunk, coalesced-ish
    for (int u = tid; u < CH_ * 16; u += 256) {
      const int t = u >> 4, r = u & 15;
      out[((size_t)h * S_ + t0 + t) * F_ + rb * 16 + r] = os[u];
    }
  }

  // final M -> d_out tail, (16,256,256)
  float* mo = Mout + (size_t)h * F_ * F_ + (size_t)ig * F_ + (sub << 4);
  #pragma unroll
  for (int u = 0; u < 4; ++u) {
    *(float4*)&mo[u << 2] =
        make_float4(M[(u << 2) + 0], M[(u << 2) + 1], M[(u << 2) + 2], M[(u << 2) + 3]);
  }
}

extern "C" void kernel_launch(void* const* d_in, const int* in_sizes, int n_in,
                              void* d_out, int out_size, void* d_ws, size_t ws_size,
                              hipStream_t stream)
{
  const float* x    = (const float*)d_in[0];
  const float* Wq   = (const float*)d_in[1];
  const float* Wk   = (const float*)d_in[2];
  const float* Wv   = (const float*)d_in[3];
  const float* Wg1  = (const float*)d_in[4];
  const float* bg1  = (const float*)d_in[5];
  const float* Wg2  = (const float*)d_in[6];
  const float* bg2  = (const float*)d_in[7];
  const float* We1  = (const float*)d_in[8];
  const float* be1  = (const float*)d_in[9];
  const float* We2  = (const float*)d_in[10];
  const float* be2  = (const float*)d_in[11];
  const float* Wa1  = (const float*)d_in[12];
  const float* ba1  = (const float*)d_in[13];
  const float* Wa2  = (const float*)d_in[14];
  const float* ba2  = (const float*)d_in[15];
  const float* Wo   = (const float*)d_in[16];
  const float* bo   = (const float*)d_in[17];
  const float* gamma= (const float*)d_in[18];
  const float* beta = (const float*)d_in[19];

  const int Mrows = NH_ * S_;               // 8192
  const size_t NTF = (size_t)Mrows * F_;    // 2097152 floats

  float* ws   = (float*)d_ws;
  float* q    = ws;             // slot 0
  float* kbuf = ws + NTF;       // slot 1: k -> kn (in place)
  float* vbuf = ws + 2 * NTF;   // slot 2: v, then v_hat
  float* tbuf = ws + 3 * NTF;   // slot 3: t1 -> se/sa -> out (scan) etc.
  float* eta  = ws + 4 * NTF;
  float* alpha= eta + Mrows;

  dim3 blk(256);
  dim3 g256(F_ / 64, Mrows / 64);   // (4,128)
  dim3 g64(DQ_ / 64, Mrows / 64);   // (1,128)

  // projections
  gemm_f32_k<<<g256, blk, 0, stream>>>(x, Wq, nullptr, q,    Mrows, F_, F_, 0);
  gemm_f32_k<<<g256, blk, 0, stream>>>(x, Wk, nullptr, kbuf, Mrows, F_, F_, 0);
  gemm_f32_k<<<g256, blk, 0, stream>>>(x, Wv, nullptr, vbuf, Mrows, F_, F_, 0);
  knorm_k<<<Mrows / 4, blk, 0, stream>>>(kbuf);

  // v_hat = silu(v@Wg1+bg1)@Wg2 + bg2   (t1 in tbuf, v_hat overwrites vbuf)
  gemm_f32_k<<<g256, blk, 0, stream>>>(vbuf, Wg1, bg1, tbuf, Mrows, F_, F_, 1);
  gemm_f32_k<<<g256, blk, 0, stream>>>(tbuf, Wg2, bg2, vbuf, Mrows, F_, F_, 0);

  // eta / alpha heads
  float* se = tbuf;                       // reuse slot 3
  float* sa = tbuf + (size_t)Mrows * DQ_;
  gemm_f32_k<<<g64, blk, 0, stream>>>(x, We1, be1, se, Mrows, DQ_, F_, 1);
  gemm_f32_k<<<g64, blk, 0, stream>>>(x, Wa1, ba1, sa, Mrows, DQ_, F_, 1);
  etaalpha_k<<<Mrows / 4, blk, 0, stream>>>(se, sa, We2, be2, Wa2, ba2, eta, alpha);

  float* yout = (float*)d_out;
  float* Mfin = yout + NTF;

  // sequential scan: out -> tbuf (se/sa dead), M -> d_out tail
  scan_k<<<dim3(16, 16), blk, 0, stream>>>(q, kbuf, vbuf, eta, alpha, tbuf, Mfin);

  // y = LN(out@Wo + bo + x); tmp reuses q (dead after scan)
  gemm_f32_k<<<g256, blk, 0, stream>>>(tbuf, Wo, bo, q, Mrows, F_, F_, 0);
  ln_k<<<Mrows / 4, blk, 0, stream>>>(q, x, gamma, beta, yout);
}